// Round 5
// baseline (6847.450 us; speedup 1.0000x reference)
//
#include <hip/hip_runtime.h>
#include <math.h>

// ---------------------------------------------------------------------------
// Sender: LSTM + Gumbel straight-through decode, 32 steps.
// Round 13 (from r12, 3779 us). Theory: LDS port is the limiter (r11 neutral
// at identical per-CU LDS traffic; r12 barrier cut small). Changes:
//  (1) B operand (weights) DIRECT global->VGPR, double-buffered reg sets
//      (8 global_load_dwordx4 per wave per K-step; +64 VGPR). Removes all
//      B ds_reads and B LDS writes: LDS port load per K-step per CU drops
//      ~62% (96KB reads+32KB writes -> 32KB+16KB). B moves to the idle
//      VMEM/L2 path. Direct fragment == old swizzled-LDS value exactly
//      (write/read XOR was an involution), so results are bit-identical.
//  (2) XCD-aware block swizzle: lin=(bx+by*nx); xcd=lin&7 owns 4 consecutive
//      bx values -> per-XCD B working set 2-2.5MB < 4MiB L2 (without this,
//      B streams from L3 and (1) would lose). Bijective for nx%8==0 (all
//      grids here: nx in {8,32}).
//  (3) A-only LDS, 4-deep pipeline (4x16KB=64KB), staged 3 ahead (2 gload_lds
//      chunks/wave/K-step), K-slot XOR swizzle kept. One barrier per K-step.
//      Region-based vmcnt: steady pre-barrier wait vmcnt(12) = {A(t+1) 2,
//      B(t) 8, A(t+2) 2}; compiler dataflow-waits cover B-reg uses. Tail
//      literals 12/12/10/8. Issue regions pinned by memory-clobber fences.
// f16 2-way split (3 MFMA/product), same accumulation order as r12
// (absmax 0.0 there).
// ---------------------------------------------------------------------------

typedef _Float16 f16;
typedef f16 f16x8 __attribute__((ext_vector_type(8)));
typedef float f32x4 __attribute__((ext_vector_type(4)));

#define F16_MIN_NORM 6.104e-5f

__device__ __forceinline__ void split_f16(float v, f16& h, f16& l) {
  f16 h0 = (fabsf(v) < F16_MIN_NORM) ? (f16)0.0f : (f16)v;
  float r = (v - (float)h0) * 4096.0f;
  h = h0; l = (f16)r;
}

__device__ __forceinline__ float sigm(float x) { return 1.0f / (1.0f + expf(-x)); }

#define GLOAD_LDS16(gsrc, ldst)                                               \
  __builtin_amdgcn_global_load_lds(                                           \
      (const __attribute__((address_space(1))) unsigned int*)(const void*)(gsrc), \
      (__attribute__((address_space(3))) unsigned int*)(void*)(ldst), 16, 0, 0)

// --------------------------- threefry / gumbel -----------------------------

__device__ __forceinline__ unsigned tf_rotl(unsigned x, int r) {
  return (x << r) | (x >> (32 - r));
}

// JAX threefry2x32-20, key (0,42), partitionable: draw = x0_out ^ x1_out.
__device__ inline float gumbel_at(unsigned idx) {
  const unsigned ks0 = 0u;
  const unsigned ks1 = 42u;
  const unsigned ks2 = 0x1BD11BDAu ^ ks0 ^ ks1;
  unsigned x0 = 0u + ks0;
  unsigned x1 = idx + ks1;
#define TFR(rot) { x0 += x1; x1 = tf_rotl(x1, rot); x1 ^= x0; }
  TFR(13) TFR(15) TFR(26) TFR(6)
  x0 += ks1; x1 += ks2 + 1u;
  TFR(17) TFR(29) TFR(16) TFR(24)
  x0 += ks2; x1 += ks0 + 2u;
  TFR(13) TFR(15) TFR(26) TFR(6)
  x0 += ks0; x1 += ks1 + 3u;
  TFR(17) TFR(29) TFR(16) TFR(24)
  x0 += ks1; x1 += ks2 + 4u;
  TFR(13) TFR(15) TFR(26) TFR(6)
  x0 += ks2; x1 += ks0 + 5u;
#undef TFR
  const unsigned bits = x0 ^ x1;
  const float f = __uint_as_float((bits >> 9) | 0x3F800000u) - 1.0f;
  const float tiny = 1.17549435082228751e-38f;
  const float u = fmaxf(tiny, f * (1.0f - tiny) + tiny);
  return -logf(-logf(u));
}

// ------------------------- setup / pack kernels ----------------------------

__global__ void init_kernel(float* __restrict__ out, const int* __restrict__ startp,
                            int* __restrict__ tok, int Tp1, int V) {
  const int b = blockIdx.x;
  const int start = *startp;
  if (threadIdx.x == 0) tok[b] = start;
  float* orow = out + (size_t)b * Tp1 * V;
  const int tq = start >> 2;
  for (int v4 = threadIdx.x; v4 < V / 4; v4 += blockDim.x) {
    float4 v = make_float4(0.f, 0.f, 0.f, 0.f);
    if (v4 == tq) ((float*)&v)[start & 3] = 1.0f;
    ((float4*)orow)[v4] = v;
  }
}

// packed gate col p: gate q=(p>>4)&3, unit u=((p>>6)<<4)+(p&15); orig row
// n' = q*H + u. wpk[p][k] = k<E ? wih[n'][k] : whh[n'][k-E], split.
__global__ void pack_gates_kernel(const float* __restrict__ wih,
                                  const float* __restrict__ whh,
                                  f16* __restrict__ w0, f16* __restrict__ w1,
                                  int E, int H, int K) {
  const int k = blockIdx.x * blockDim.x + threadIdx.x;
  const int p = blockIdx.y;
  if (k >= K) return;
  const int n = ((p >> 4) & 3) * H + ((p >> 6) << 4) + (p & 15);
  const float v = (k < E) ? wih[(size_t)n * E + k] : whh[(size_t)n * H + (k - E)];
  f16 h, l; split_f16(v, h, l);
  w0[(size_t)p * K + k] = h;
  w1[(size_t)p * K + k] = l;
}

__global__ void pack_bias_kernel(const float* __restrict__ bih,
                                 const float* __restrict__ bhh,
                                 float* __restrict__ bi, float* __restrict__ bh, int H) {
  const int p = blockIdx.x * blockDim.x + threadIdx.x;
  const int n = ((p >> 4) & 3) * H + ((p >> 6) << 4) + (p & 15);
  bi[p] = bih[n];
  bh[p] = bhh[n];
}

__global__ void split_kernel(const float* __restrict__ in,
                             f16* __restrict__ o0, f16* __restrict__ o1, int n) {
  const int i = blockIdx.x * blockDim.x + threadIdx.x;
  if (i < n) { f16 h, l; split_f16(in[i], h, l); o0[i] = h; o1[i] = l; }
}

// ----------------------- shared K-loop building block ----------------------
// block 512 thr / 8 waves, tile 128x128, BK=32.
// A: LDS 4-deep (4 x 16KB), staged 3 ahead, 2 gload_lds chunks/wave/K-step,
//    K-slot XOR swizzle (LDS[row][slot] holds global slot^((row>>1)&3)):
//      stage source slot = (lane&3) ^ ((lane>>3)&3)   (srow = lane>>2)
//      read slot         = (lane>>4) ^ ((lane>>1)&3)  (row&15 == lane&15)
// B: direct global->VGPR, 2 reg sets, 8 loads/wave/K-step (4 j x 2 planes),
//    fragment = w[bn+wn+j*16+(lane&15)][k0 + (lane>>4)*8 .. +8] (no swizzle).
// Wave (wr=wid&3, wc=wid>>2) computes rows [wr*32,+32) x cols [wc*64,+64).

#define MFMA_DECLS                                                            \
  const int tid  = threadIdx.x;                                               \
  const int lane = tid & 63;                                                  \
  const int wid  = tid >> 6;                                                  \
  const int nx_  = gridDim.x;                                                 \
  const int lin_ = blockIdx.x + blockIdx.y * nx_;                             \
  const int nx8_ = nx_ >> 3;                                                  \
  const int sh_  = (nx8_ == 4) ? 2 : ((nx8_ == 2) ? 1 : 0);                   \
  const int bx_  = (lin_ & 7) * nx8_ + ((lin_ >> 3) & (nx8_ - 1));            \
  const int by_  = (lin_ >> 3) >> sh_;                                        \
  const int bm   = by_ * 128;                                                 \
  const int bn   = bx_ * 128;                                                 \
  const int wm   = (wid & 3) * 32;                                            \
  const int wn   = (wid >> 2) * 64;                                           \
  const int fr   = lane & 15;                                                 \
  const int fk   = (((lane >> 4) ^ ((lane >> 1) & 3)) * 8);                   \
  const int srow = lane >> 2;                                                 \
  const int scol = (((lane & 3) ^ ((lane >> 3) & 3)) * 8);                    \
  f16x8 br0[2][4], br1[2][4];                                                 \
  f32x4 acc0[2][4], acc1[2][4];                                               \
  _Pragma("unroll") for (int i = 0; i < 2; ++i)                               \
  _Pragma("unroll") for (int j = 0; j < 4; ++j) {                             \
    acc0[i][j] = (f32x4)0.0f; acc1[i][j] = (f32x4)0.0f; }

#define MFMA_LDS_DECL                                                         \
  __shared__ f16 ldsA0[4][128][32], ldsA1[4][128][32];

// B pointer setup: per-lane bases for the 8 fragment streams; advance by
// immediate offsets (c*32 f16 = c*64 B, 13-bit imm) + bump of 128/4 steps.
#define MFMA_BP_DECL(Bsrc0, Bsrc1, ldb, kb0)                                  \
  const f16* bp0[4]; const f16* bp1[4];                                       \
  _Pragma("unroll") for (int j = 0; j < 4; ++j) {                             \
    const int brow = bn + wn + j * 16 + fr;                                   \
    bp0[j] = (Bsrc0) + (size_t)brow * (ldb) + (kb0) + (lane >> 4) * 8;        \
    bp1[j] = (Bsrc1) + (size_t)brow * (ldb) + (kb0) + (lane >> 4) * 8;        \
  }

#define LOADB_C(set, c)                                                       \
  { _Pragma("unroll") for (int j = 0; j < 4; ++j) {                           \
      br0[set][j] = *(const f16x8*)(bp0[j] + (c) * 32);                       \
      br1[set][j] = *(const f16x8*)(bp1[j] + (c) * 32);                       \
    } }

#define BUMPB                                                                 \
  { _Pragma("unroll") for (int j = 0; j < 4; ++j) {                           \
      bp0[j] += 128; bp1[j] += 128;                                           \
    } }

// A staging: 16 chunks (8 hi-plane, 8 lo-plane), 2 per wave.
#define MFMA_STAGE_A(buf, a0s, a1s, lda, ka)                                  \
  { const int ch_ = wid * 2;                                                  \
    if (ch_ < 8) {                                                            \
      GLOAD_LDS16((a0s) + (size_t)(bm + ch_ * 16 + srow) * (lda) + (ka) + scol,      \
                  &ldsA0[(buf)][ch_ * 16][0]);                                \
      GLOAD_LDS16((a0s) + (size_t)(bm + (ch_ + 1) * 16 + srow) * (lda) + (ka) + scol,\
                  &ldsA0[(buf)][(ch_ + 1) * 16][0]);                          \
    } else {                                                                  \
      GLOAD_LDS16((a1s) + (size_t)(bm + (ch_ - 8) * 16 + srow) * (lda) + (ka) + scol,\
                  &ldsA1[(buf)][(ch_ - 8) * 16][0]);                          \
      GLOAD_LDS16((a1s) + (size_t)(bm + (ch_ - 7) * 16 + srow) * (lda) + (ka) + scol,\
                  &ldsA1[(buf)][(ch_ - 7) * 16][0]);                          \
    } }

#define MFMA_COMPUTE_FROM(buf, set)                                           \
  {                                                                           \
    f16x8 a0[2], a1[2];                                                       \
    _Pragma("unroll") for (int i = 0; i < 2; ++i) {                           \
      a0[i] = *(const f16x8*)&ldsA0[(buf)][wm + i * 16 + fr][fk];             \
      a1[i] = *(const f16x8*)&ldsA1[(buf)][wm + i * 16 + fr][fk];             \
    }                                                                         \
    _Pragma("unroll") for (int i = 0; i < 2; ++i)                             \
    _Pragma("unroll") for (int j = 0; j < 4; ++j) {                           \
      acc0[i][j] = __builtin_amdgcn_mfma_f32_16x16x32_f16(a0[i], br0[set][j], acc0[i][j], 0, 0, 0); \
      acc1[i][j] = __builtin_amdgcn_mfma_f32_16x16x32_f16(a0[i], br1[set][j], acc1[i][j], 0, 0, 0); \
      acc1[i][j] = __builtin_amdgcn_mfma_f32_16x16x32_f16(a1[i], br0[set][j], acc1[i][j], 0, 0, 0); \
    }                                                                         \
  }

// One K-step: counted wait (A cross-wave visibility) -> barrier -> issue
// B(t+1) regs + A(t+3) stage (hidden under MFMA; region pinned by fences)
// -> MFMA cluster. Compiler dataflow inserts its own waits for B-reg uses.
#define PIPE_ITER(bufc, set, VM, DO_B, DO_A)                                  \
  asm volatile("s_waitcnt vmcnt(" #VM ")" ::: "memory");                      \
  __builtin_amdgcn_s_barrier();                                               \
  asm volatile("" ::: "memory");                                              \
  DO_B                                                                        \
  DO_A                                                                        \
  __builtin_amdgcn_s_setprio(1);                                              \
  MFMA_COMPUTE_FROM(bufc, set)                                                \
  __builtin_amdgcn_s_setprio(0);                                              \
  asm volatile("" ::: "memory");

// Pipeline: A staged 3 ahead (bufs t&3), B 1 ahead (sets t&1). NT%4==0, NT>=8.
// STAGE_T(buf, t) must be #defined per kernel (A only).
#define PIPE(NT)                                                              \
  STAGE_T(0, 0) STAGE_T(1, 1)                                                 \
  LOADB_C(0, 0)                                                               \
  STAGE_T(2, 2)                                                               \
  {                                                                           \
    int tt = 0;                                                               \
    for (; tt < (NT) - 4; tt += 4) {                                          \
      PIPE_ITER(0, 0, 12, LOADB_C(1, 1), STAGE_T(3, tt + 3))                  \
      PIPE_ITER(1, 1, 12, LOADB_C(0, 2), STAGE_T(0, tt + 4))                  \
      PIPE_ITER(2, 0, 12, LOADB_C(1, 3), STAGE_T(1, tt + 5))                  \
      PIPE_ITER(3, 1, 12, LOADB_C(0, 4), STAGE_T(2, tt + 6))                  \
      BUMPB                                                                   \
    }                                                                         \
    PIPE_ITER(0, 0, 12, LOADB_C(1, 1), STAGE_T(3, tt + 3))                    \
    PIPE_ITER(1, 1, 12, LOADB_C(0, 2), {})                                    \
    PIPE_ITER(2, 0, 10, LOADB_C(1, 3), {})                                    \
    PIPE_ITER(3, 1, 8, {}, {})                                                \
  }

// ------------------- h0 GEMM: h0 = t @ aff_w^T + aff_b ---------------------
__global__ __launch_bounds__(512, 2) void h0_kernel(
    const f16* __restrict__ t0, const f16* __restrict__ t1, int F,
    const f16* __restrict__ aw0, const f16* __restrict__ aw1,
    const float* __restrict__ affb,
    f16* __restrict__ h0p, f16* __restrict__ h1p, int H,
    float* __restrict__ czero)
{
  MFMA_LDS_DECL
  MFMA_DECLS
  MFMA_BP_DECL(aw0, aw1, F, 0)
  const int NT = F / 32;
#define STAGE_T(buf, t) MFMA_STAGE_A(buf, t0, t1, F, (t) * 32)
  PIPE(NT)
#undef STAGE_T
  const int q4 = (lane >> 4) * 4;
  const float s12 = 1.0f / 4096.0f;
  const int cn0 = bn + wn;
#pragma unroll
  for (int j = 0; j < 4; ++j) {
    const int col = cn0 + j * 16 + fr;
    const float bb = affb[col];
#pragma unroll
    for (int i = 0; i < 2; ++i) {
#pragma unroll
      for (int r = 0; r < 4; ++r) {
        const int row = bm + wm + i * 16 + q4 + r;
        const float v = (acc0[i][j][r] + acc1[i][j][r] * s12) + bb;
        f16 hh, hl; split_f16(v, hh, hl);
        const size_t off = (size_t)row * H + col;
        h0p[off] = hh; h1p[off] = hl;
        czero[off] = 0.0f;
      }
    }
  }
}

// ------- gih table GEMM: gih[v][p] = emb[v].wih[n(p)] + bih + bhh ----------
__global__ __launch_bounds__(512, 2) void gih_kernel(
    const f16* __restrict__ e0, const f16* __restrict__ e1, int E,
    const f16* __restrict__ w0, const f16* __restrict__ w1, int K,
    const float* __restrict__ bi, const float* __restrict__ bh,
    float* __restrict__ gih, int NP)
{
  MFMA_LDS_DECL
  MFMA_DECLS
  MFMA_BP_DECL(w0, w1, K, 0)
  const int NT = E / 32;
#define STAGE_T(buf, t) MFMA_STAGE_A(buf, e0, e1, E, (t) * 32)
  PIPE(NT)
#undef STAGE_T
  const int q4 = (lane >> 4) * 4;
  const float s12 = 1.0f / 4096.0f;
  const int cn0 = bn + wn;
#pragma unroll
  for (int j = 0; j < 4; ++j) {
    const int col = cn0 + j * 16 + fr;
    const float bb = bi[col] + bh[col];
#pragma unroll
    for (int i = 0; i < 2; ++i)
#pragma unroll
      for (int r = 0; r < 4; ++r) {
        const int row = bm + wm + i * 16 + q4 + r;
        gih[(size_t)row * NP + col] = (acc0[i][j][r] + acc1[i][j][r] * s12) + bb;
      }
  }
}

// ---------------- gates GEMM + fused LSTM cell epilogue --------------------
// gates = h @ w_hh^T (K=H) + gih[tok[row]] (embedding term + both biases).
__global__ __launch_bounds__(512, 2) void gates_kernel(
    const f16* __restrict__ hin0, const f16* __restrict__ hin1, int H,
    const f16* __restrict__ w0, const f16* __restrict__ w1, int K, int E,
    const float* __restrict__ gih, int NP, const int* __restrict__ tok,
    float* __restrict__ cbuf,
    f16* __restrict__ hout0, f16* __restrict__ hout1)
{
  MFMA_LDS_DECL
  MFMA_DECLS
  MFMA_BP_DECL(w0, w1, K, E)
  const int NT = H / 32;
#define STAGE_T(buf, t) MFMA_STAGE_A(buf, hin0, hin1, H, (t) * 32)
  PIPE(NT)
#undef STAGE_T
  // epilogue: packed cols -> unit u = (cn0>>2)+fr, gate q = j.
  const int q4 = (lane >> 4) * 4;
  const float s12 = 1.0f / 4096.0f;
  const int cn0 = bn + wn;
  const int nunit = (cn0 >> 2) + fr;
#pragma unroll
  for (int i = 0; i < 2; ++i) {
#pragma unroll
    for (int r = 0; r < 4; ++r) {
      const int row = bm + wm + i * 16 + q4 + r;
      const float* gr = gih + (size_t)tok[row] * NP + cn0 + fr;
      float gv[4];
#pragma unroll
      for (int j = 0; j < 4; ++j)
        gv[j] = (acc0[i][j][r] + acc1[i][j][r] * s12) + gr[j * 16];
      const size_t off = (size_t)row * H + nunit;
      const float c = cbuf[off];
      const float cn = __fadd_rn(__fmul_rn(sigm(gv[1]), c),
                                 __fmul_rn(sigm(gv[0]), tanhf(gv[2])));
      const float hn = __fmul_rn(sigm(gv[3]), tanhf(cn));
      cbuf[off] = cn;
      f16 hh, hl; split_f16(hn, hh, hl);
      hout0[off] = hh; hout1[off] = hl;
    }
  }
}

// ------------- logits GEMM + fused argmax-partials epilogue ----------------
__global__ __launch_bounds__(512, 2) void logits_kernel(
    const f16* __restrict__ h0p, const f16* __restrict__ h1p, int H,
    const f16* __restrict__ w0, const f16* __restrict__ w1,
    const float* __restrict__ lpb,
    float* __restrict__ partM, int* __restrict__ partI,
    int step, int B, int V)
{
  MFMA_LDS_DECL
  MFMA_DECLS
  MFMA_BP_DECL(w0, w1, H, 0)
  const int NT = H / 32;
#define STAGE_T(buf, t) MFMA_STAGE_A(buf, h0p, h1p, H, (t) * 32)
  PIPE(NT)
#undef STAGE_T
  const int q4 = (lane >> 4) * 4;
  const float s12 = 1.0f / 4096.0f;
  const int cn0 = bn + wn;
  float bv[4];
#pragma unroll
  for (int j = 0; j < 4; ++j) bv[j] = lpb[cn0 + j * 16 + fr];
  // w = logit + gumbel, overwrite acc0
#pragma unroll
  for (int i = 0; i < 2; ++i)
#pragma unroll
    for (int j = 0; j < 4; ++j) {
      const int col = cn0 + j * 16 + fr;
#pragma unroll
      for (int r = 0; r < 4; ++r) {
        const int row = bm + wm + i * 16 + q4 + r;
        const float logit = (acc0[i][j][r] + acc1[i][j][r] * s12) + bv[j];
        const unsigned gidx = ((unsigned)(step * B + row)) * (unsigned)V + (unsigned)col;
        acc0[i][j][r] = logit + gumbel_at(gidx);
      }
    }
  // per-row argmax over this wave's 64 cols (within each 16-lane group).
  // sc == 1.0 exactly, so no denominator partials needed.
  const int grp = cn0 >> 6;   // 64 col-groups of 64
#pragma unroll
  for (int i = 0; i < 2; ++i) {
#pragma unroll
    for (int r = 0; r < 4; ++r) {
      float mx = -INFINITY; int ix = 0;
#pragma unroll
      for (int j = 0; j < 4; ++j) {
        const float w = acc0[i][j][r];
        const int col = cn0 + j * 16 + fr;
        if (w > mx) { mx = w; ix = col; }
      }
#pragma unroll
      for (int m = 1; m < 16; m <<= 1) {
        const float om = __shfl_xor(mx, m, 64);
        const int oi = __shfl_xor(ix, m, 64);
        if (om > mx || (om == mx && oi < ix)) { mx = om; ix = oi; }
      }
      if (fr == 0) {
        const int row = bm + wm + i * 16 + q4 + r;
        partM[(size_t)row * 64 + grp] = mx;
        partI[(size_t)row * 64 + grp] = ix;
      }
    }
  }
}

// ----------- finalize: argmax reduce, write one-hot, publish tok -----------
__global__ __launch_bounds__(256) void finalize_kernel(
    const float* __restrict__ partM, const int* __restrict__ partI,
    float* __restrict__ out, int* __restrict__ tok,
    int step, int Tp1, int V)
{
  const int b = blockIdx.x;
  const int tid = threadIdx.x;
  __shared__ int s_tok;

  if (tid < 64) {
    float mx = partM[(size_t)b * 64 + tid];
    int ix = partI[(size_t)b * 64 + tid];
#pragma unroll
    for (int m = 1; m < 64; m <<= 1) {
      const float om = __shfl_xor(mx, m, 64);
      const int oi = __shfl_xor(ix, m, 64);
      if (om > mx || (om == mx && oi < ix)) { mx = om; ix = oi; }
    }
    if (tid == 0) { s_tok = ix; tok[b] = ix; }
  }
  __syncthreads();
  const int tk = s_tok;

  // one-hot write with exact 1.0 (sc == (1-y)+y == 1.0f identically)
  float* orow = out + ((size_t)b * Tp1 + step + 1) * V;
  const int tq = tk >> 2;
#pragma unroll
  for (int j = 0; j < 4; ++j) {
    const int idx = tid + 256 * j;
    float4 v = make_float4(0.f, 0.f, 0.f, 0.f);
    if (idx == tq) ((float*)&v)[tk & 3] = 1.0f;
    ((float4*)orow)[idx] = v;
  }
}

// ------------------------------- host side ---------------------------------

extern "C" void kernel_launch(void* const* d_in, const int* in_sizes, int n_in,
                              void* d_out, int out_size, void* d_ws, size_t ws_size,
                              hipStream_t stream) {
  const float* t     = (const float*)d_in[0];
  const float* emb   = (const float*)d_in[1];
  const float* affw  = (const float*)d_in[2];
  const float* affb  = (const float*)d_in[3];
  const float* wih   = (const float*)d_in[4];
  const float* whh   = (const float*)d_in[5];
  const float* bih   = (const float*)d_in[6];
  const float* bhh   = (const float*)d_in[7];
  const float* lpw   = (const float*)d_in[8];
  const float* lpb   = (const float*)d_in[9];
  const int*   start = (const int*)d_in[10];
  float* out = (float*)d_out;

  const int H = in_sizes[3];             // 1024
  const int V = in_sizes[9];             // 4096
  const int E = in_sizes[1] / V;         // 256
  const int F = in_sizes[2] / H;         // 2048
  const int B = in_sizes[0] / F;         // 1024
  const int Tp1 = out_size / (B * V);    // 33
  const int T = Tp1 - 1;                 // 32
  const int KG = E + H;                  // 1280
  const int NP = 4 * H;                  // 4096 packed gate cols

  // ---- workspace layout (~190 MB) ----
  char* p = (char*)d_ws;
  float* gihb  = (float*)p; p += (size_t)V * NP * 4;          // 64 MB gih table
  float* cbuf  = (float*)p; p += (size_t)B * H * 4;           // 4 MB
  f16* hA0[2]; f16* hA1[2];
  hA0[0] = (f16*)p; p += (size_t)B * H * 2;
  hA1[0] = (f16*)p; p += (size_t)B * H * 2;
  hA0[1] = (f16*)p; p += (size_t)B * H * 2;
  hA1[1] = (f16*)p; p += (size_t)B * H * 2;                   // 8 MB
  f16* wg0 = (f16*)p; p += (size_t)V * KG * 2;                // 21 MB packed gates
  f16* wg1 = (f16*)p; p += (size_t)V * KG * 2;
  f16* wl0 = (f16*)p; p += (size_t)V * H * 2;                 // 16 MB lp_w
  f16* wl1 = (f16*)p; p += (size_t)V * H * 2;
  f16* t0  = (f16*)p; p += (size_t)B * F * 2;                 // 8 MB t planes
  f16* t1  = (f16*)p; p += (size_t)B * F * 2;
  f16* aw0 = (f16*)p; p += (size_t)H * F * 2;                 // 8 MB aff_w planes
  f16* aw1 = (f16*)p; p += (size_t)H * F * 2;
  f16* em0 = (f16*)p; p += (size_t)V * E * 2;                 // 4 MB emb planes
  f16* em1 = (f16*)p; p += (size_t)V * E * 2;
  float* bgi = (float*)p; p += (size_t)NP * 4;
  float* bgh = (float*)p; p += (size_t)NP * 4;
  float* partM = (float*)p; p += (size_t)B * 64 * 4;
  int*   partI = (int*)p;   p += (size_t)B * 64 * 4;
  int*   tokb  = (int*)p;   p += (size_t)B * 4;
  (void)ws_size; (void)n_in;

  // ---- setup ----
  init_kernel<<<B, 256, 0, stream>>>(out, start, tokb, Tp1, V);
  pack_gates_kernel<<<dim3((KG + 255) / 256, NP), 256, 0, stream>>>(
      wih, whh, wg0, wg1, E, H, KG);
  pack_bias_kernel<<<NP / 256, 256, 0, stream>>>(bih, bhh, bgi, bgh, H);
  split_kernel<<<(V * H + 255) / 256, 256, 0, stream>>>(lpw, wl0, wl1, V * H);
  split_kernel<<<(B * F + 255) / 256, 256, 0, stream>>>(t, t0, t1, B * F);
  split_kernel<<<(H * F + 255) / 256, 256, 0, stream>>>(affw, aw0, aw1, H * F);
  split_kernel<<<(V * E + 255) / 256, 256, 0, stream>>>(emb, em0, em1, V * E);
  // h0 = t @ aff_w^T + aff_b -> split into hA[0]; zero cbuf
  h0_kernel<<<dim3(H / 128, B / 128), 512, 0, stream>>>(
      t0, t1, F, aw0, aw1, affb, hA0[0], hA1[0], H, cbuf);
  // gih = emb @ w_ih^T + b_ih + b_hh (packed cols), f32
  gih_kernel<<<dim3(NP / 128, V / 128), 512, 0, stream>>>(
      em0, em1, E, wg0, wg1, KG, bgi, bgh, gihb, NP);

  for (int s = 0; s < T; ++s) {
    const int cur = s & 1, nxt = (s + 1) & 1;
    gates_kernel<<<dim3(NP / 128, B / 128), 512, 0, stream>>>(
        hA0[cur], hA1[cur], H, wg0, wg1, KG, E, gihb, NP, tokb,
        cbuf, hA0[nxt], hA1[nxt]);
    logits_kernel<<<dim3(V / 128, B / 128), 512, 0, stream>>>(
        hA0[nxt], hA1[nxt], H, wl0, wl1, lpb,
        partM, partI, s, B, V);
    finalize_kernel<<<B, 256, 0, stream>>>(
        partM, partI, out, tokb, s, Tp1, V);
  }
}

// Round 6
// 4125.348 us; speedup vs baseline: 1.6598x; 1.6598x over previous
//
#include <hip/hip_runtime.h>
#include <math.h>

// ---------------------------------------------------------------------------
// Sender: LSTM + Gumbel straight-through decode, 32 steps.
// Round 14 (r13 regressed 6847 -> REVERTED to r12 base, 3779 us).
// r13 lesson: B direct-to-VGPR quadruplicates B traffic (4 waves share each
// col-half) - the wide operand must stay in LDS. Changes vs r12:
//  (1) 64x64 waves: 4 waves/block (256 thr), same 128x128 tile. Per wave
//      per K-step: 16 ds_read_b128 feeding 48 MFMA (reads/MFMA 0.5 -> 0.33).
//      Per-block LDS reads/K-step 96 -> 64 (-33%), MFMA unchanged, global
//      traffic unchanged. acc grows to 4x4x2 f32x4 (128 VGPR), total ~230,
//      capped by __launch_bounds__(256,2).
//  (2) 2-deep LDS pipeline (2 x 32 KB = 64 KB) -> 2 blocks/CU capacity:
//      cross-block overlap returns (one block's stage-wait/barrier hides
//      under the other's MFMA). Wait-before-barrier ordering kept (wave
//      drains OWN stage loads, then barrier => cross-wave visibility).
//  (3) Single barrier per K-step, stage issued after barrier into the
//      buffer freed by the previous compute (hand-unrolled x2, literal
//      buffer indices). K-slot XOR swizzle unchanged.
// f16 2-way split (3 MFMA/product), same per-element accumulation order as
// r12 (absmax 0.0 there).
// ---------------------------------------------------------------------------

typedef _Float16 f16;
typedef f16 f16x8 __attribute__((ext_vector_type(8)));
typedef float f32x4 __attribute__((ext_vector_type(4)));

#define F16_MIN_NORM 6.104e-5f

__device__ __forceinline__ void split_f16(float v, f16& h, f16& l) {
  f16 h0 = (fabsf(v) < F16_MIN_NORM) ? (f16)0.0f : (f16)v;
  float r = (v - (float)h0) * 4096.0f;
  h = h0; l = (f16)r;
}

__device__ __forceinline__ float sigm(float x) { return 1.0f / (1.0f + expf(-x)); }

#define GLOAD_LDS16(gsrc, ldst)                                               \
  __builtin_amdgcn_global_load_lds(                                           \
      (const __attribute__((address_space(1))) unsigned int*)(const void*)(gsrc), \
      (__attribute__((address_space(3))) unsigned int*)(void*)(ldst), 16, 0, 0)

// --------------------------- threefry / gumbel -----------------------------

__device__ __forceinline__ unsigned tf_rotl(unsigned x, int r) {
  return (x << r) | (x >> (32 - r));
}

// JAX threefry2x32-20, key (0,42), partitionable: draw = x0_out ^ x1_out.
__device__ inline float gumbel_at(unsigned idx) {
  const unsigned ks0 = 0u;
  const unsigned ks1 = 42u;
  const unsigned ks2 = 0x1BD11BDAu ^ ks0 ^ ks1;
  unsigned x0 = 0u + ks0;
  unsigned x1 = idx + ks1;
#define TFR(rot) { x0 += x1; x1 = tf_rotl(x1, rot); x1 ^= x0; }
  TFR(13) TFR(15) TFR(26) TFR(6)
  x0 += ks1; x1 += ks2 + 1u;
  TFR(17) TFR(29) TFR(16) TFR(24)
  x0 += ks2; x1 += ks0 + 2u;
  TFR(13) TFR(15) TFR(26) TFR(6)
  x0 += ks0; x1 += ks1 + 3u;
  TFR(17) TFR(29) TFR(16) TFR(24)
  x0 += ks1; x1 += ks2 + 4u;
  TFR(13) TFR(15) TFR(26) TFR(6)
  x0 += ks2; x1 += ks0 + 5u;
#undef TFR
  const unsigned bits = x0 ^ x1;
  const float f = __uint_as_float((bits >> 9) | 0x3F800000u) - 1.0f;
  const float tiny = 1.17549435082228751e-38f;
  const float u = fmaxf(tiny, f * (1.0f - tiny) + tiny);
  return -logf(-logf(u));
}

// ------------------------- setup / pack kernels ----------------------------

__global__ void init_kernel(float* __restrict__ out, const int* __restrict__ startp,
                            int* __restrict__ tok, int Tp1, int V) {
  const int b = blockIdx.x;
  const int start = *startp;
  if (threadIdx.x == 0) tok[b] = start;
  float* orow = out + (size_t)b * Tp1 * V;
  const int tq = start >> 2;
  for (int v4 = threadIdx.x; v4 < V / 4; v4 += blockDim.x) {
    float4 v = make_float4(0.f, 0.f, 0.f, 0.f);
    if (v4 == tq) ((float*)&v)[start & 3] = 1.0f;
    ((float4*)orow)[v4] = v;
  }
}

// packed gate col p: gate q=(p>>4)&3, unit u=((p>>6)<<4)+(p&15); orig row
// n' = q*H + u. wpk[p][k] = k<E ? wih[n'][k] : whh[n'][k-E], split.
__global__ void pack_gates_kernel(const float* __restrict__ wih,
                                  const float* __restrict__ whh,
                                  f16* __restrict__ w0, f16* __restrict__ w1,
                                  int E, int H, int K) {
  const int k = blockIdx.x * blockDim.x + threadIdx.x;
  const int p = blockIdx.y;
  if (k >= K) return;
  const int n = ((p >> 4) & 3) * H + ((p >> 6) << 4) + (p & 15);
  const float v = (k < E) ? wih[(size_t)n * E + k] : whh[(size_t)n * H + (k - E)];
  f16 h, l; split_f16(v, h, l);
  w0[(size_t)p * K + k] = h;
  w1[(size_t)p * K + k] = l;
}

__global__ void pack_bias_kernel(const float* __restrict__ bih,
                                 const float* __restrict__ bhh,
                                 float* __restrict__ bi, float* __restrict__ bh, int H) {
  const int p = blockIdx.x * blockDim.x + threadIdx.x;
  const int n = ((p >> 4) & 3) * H + ((p >> 6) << 4) + (p & 15);
  bi[p] = bih[n];
  bh[p] = bhh[n];
}

__global__ void split_kernel(const float* __restrict__ in,
                             f16* __restrict__ o0, f16* __restrict__ o1, int n) {
  const int i = blockIdx.x * blockDim.x + threadIdx.x;
  if (i < n) { f16 h, l; split_f16(in[i], h, l); o0[i] = h; o1[i] = l; }
}

// ----------------------- shared K-loop building block ----------------------
// block 256 thr / 4 waves, tile 128x128, BK=32, 2-deep LDS pipeline (64 KB).
// Staging: 32 1KB chunks; wave w stages plane w (A0/A1/B0/B1), 8 chunks each.
// Wave (wr=wid&1, wc=wid>>1) computes rows [wr*64,+64) x cols [wc*64,+64).
// Swizzle: LDS[row][slot] holds global 16B-slot (slot ^ ((row>>1)&3)).
//   stage source slot = (lane&3) ^ ((lane>>3)&3)   (srow = lane>>2)
//   read slot         = (lane>>4) ^ ((lane>>1)&3)  (row & 15 == lane & 15)

#define MFMA_DECLS                                                            \
  const int tid  = threadIdx.x;                                               \
  const int lane = tid & 63;                                                  \
  const int wid  = tid >> 6;                                                  \
  const int bm   = blockIdx.y * 128;                                          \
  const int bn   = blockIdx.x * 128;                                          \
  const int wm   = (wid & 1) * 64;                                            \
  const int wn   = (wid >> 1) * 64;                                           \
  const int fr   = lane & 15;                                                 \
  const int fk   = (((lane >> 4) ^ ((lane >> 1) & 3)) * 8);                   \
  const int srow = lane >> 2;                                                 \
  const int scol = (((lane & 3) ^ ((lane >> 3) & 3)) * 8);                    \
  f32x4 acc0[4][4], acc1[4][4];                                               \
  _Pragma("unroll") for (int i = 0; i < 4; ++i)                               \
  _Pragma("unroll") for (int j = 0; j < 4; ++j) {                             \
    acc0[i][j] = (f32x4)0.0f; acc1[i][j] = (f32x4)0.0f; }

#define MFMA_LDS_DECL                                                         \
  __shared__ f16 ldsA0[2][128][32], ldsA1[2][128][32],                        \
                 ldsB0[2][128][32], ldsB1[2][128][32];

// Issue-only staging into buffer `buf` (no barriers here). Wave w stages
// plane w: 8 chunks of 16 rows. Branches are wave-uniform.
#define MFMA_STAGE_TO(buf, a0s, a1s, lda, ka, b0s, b1s, ldb, kb)              \
  { if (wid == 0) {                                                           \
      _Pragma("unroll") for (int c = 0; c < 8; ++c)                           \
        GLOAD_LDS16((a0s) + (size_t)(bm + c * 16 + srow) * (lda) + (ka) + scol, \
                    &ldsA0[(buf)][c * 16][0]);                                \
    } else if (wid == 1) {                                                    \
      _Pragma("unroll") for (int c = 0; c < 8; ++c)                           \
        GLOAD_LDS16((a1s) + (size_t)(bm + c * 16 + srow) * (lda) + (ka) + scol, \
                    &ldsA1[(buf)][c * 16][0]);                                \
    } else if (wid == 2) {                                                    \
      _Pragma("unroll") for (int c = 0; c < 8; ++c)                           \
        GLOAD_LDS16((b0s) + (size_t)(bn + c * 16 + srow) * (ldb) + (kb) + scol, \
                    &ldsB0[(buf)][c * 16][0]);                                \
    } else {                                                                  \
      _Pragma("unroll") for (int c = 0; c < 8; ++c)                           \
        GLOAD_LDS16((b1s) + (size_t)(bn + c * 16 + srow) * (ldb) + (kb) + scol, \
                    &ldsB1[(buf)][c * 16][0]);                                \
    } }

#define MFMA_COMPUTE_FROM(buf)                                                \
  {                                                                           \
    f16x8 a0[4], a1[4], b0[4], b1[4];                                         \
    _Pragma("unroll") for (int i = 0; i < 4; ++i) {                           \
      a0[i] = *(const f16x8*)&ldsA0[(buf)][wm + i * 16 + fr][fk];             \
      a1[i] = *(const f16x8*)&ldsA1[(buf)][wm + i * 16 + fr][fk];             \
    }                                                                         \
    _Pragma("unroll") for (int j = 0; j < 4; ++j) {                           \
      b0[j] = *(const f16x8*)&ldsB0[(buf)][wn + j * 16 + fr][fk];             \
      b1[j] = *(const f16x8*)&ldsB1[(buf)][wn + j * 16 + fr][fk];             \
    }                                                                         \
    _Pragma("unroll") for (int i = 0; i < 4; ++i)                             \
    _Pragma("unroll") for (int j = 0; j < 4; ++j) {                           \
      acc0[i][j] = __builtin_amdgcn_mfma_f32_16x16x32_f16(a0[i], b0[j], acc0[i][j], 0, 0, 0); \
      acc1[i][j] = __builtin_amdgcn_mfma_f32_16x16x32_f16(a0[i], b1[j], acc1[i][j], 0, 0, 0); \
      acc1[i][j] = __builtin_amdgcn_mfma_f32_16x16x32_f16(a1[i], b0[j], acc1[i][j], 0, 0, 0); \
    }                                                                         \
  }

// One K-step: drain own stage-t loads (only stage t is in flight at the
// wait: 2-deep) -> barrier (cross-wave visibility of buf t AND confirms
// everyone finished computing the buffer we stage into next) -> issue stage
// t+1 into the freed buffer (flies under the MFMA cluster) -> MFMA.
#define PIPE_ITER(bufc, bufs, DO_STAGE)                                       \
  asm volatile("s_waitcnt vmcnt(0)" ::: "memory");                            \
  __builtin_amdgcn_s_barrier();                                               \
  asm volatile("" ::: "memory");                                              \
  DO_STAGE                                                                    \
  asm volatile("" ::: "memory");                                              \
  __builtin_amdgcn_s_setprio(1);                                              \
  MFMA_COMPUTE_FROM(bufc)                                                     \
  __builtin_amdgcn_s_setprio(0);                                              \
  asm volatile("" ::: "memory");

// 2-deep pipeline, hand-unrolled x2 with literal buffer indices.
// NT must be even, NT >= 2. STAGE_T(buf, t) #defined per kernel.
#define PIPE(NT)                                                              \
  STAGE_T(0, 0)                                                               \
  for (int tt = 0; tt < (NT); tt += 2) {                                      \
    PIPE_ITER(0, 1, if (tt + 1 < (NT)) { STAGE_T(1, tt + 1) })                \
    PIPE_ITER(1, 0, if (tt + 2 < (NT)) { STAGE_T(0, tt + 2) })                \
  }

// ------------------- h0 GEMM: h0 = t @ aff_w^T + aff_b ---------------------
__global__ __launch_bounds__(256, 2) void h0_kernel(
    const f16* __restrict__ t0, const f16* __restrict__ t1, int F,
    const f16* __restrict__ aw0, const f16* __restrict__ aw1,
    const float* __restrict__ affb,
    f16* __restrict__ h0p, f16* __restrict__ h1p, int H,
    float* __restrict__ czero)
{
  MFMA_LDS_DECL
  MFMA_DECLS
  const int NT = F / 32;
#define STAGE_T(buf, t) MFMA_STAGE_TO(buf, t0, t1, F, (t) * 32, aw0, aw1, F, (t) * 32)
  PIPE(NT)
#undef STAGE_T
  const int q4 = (lane >> 4) * 4;
  const float s12 = 1.0f / 4096.0f;
  const int cn0 = bn + wn;
#pragma unroll
  for (int j = 0; j < 4; ++j) {
    const int col = cn0 + j * 16 + fr;
    const float bb = affb[col];
#pragma unroll
    for (int i = 0; i < 4; ++i) {
#pragma unroll
      for (int r = 0; r < 4; ++r) {
        const int row = bm + wm + i * 16 + q4 + r;
        const float v = (acc0[i][j][r] + acc1[i][j][r] * s12) + bb;
        f16 hh, hl; split_f16(v, hh, hl);
        const size_t off = (size_t)row * H + col;
        h0p[off] = hh; h1p[off] = hl;
        czero[off] = 0.0f;
      }
    }
  }
}

// ------- gih table GEMM: gih[v][p] = emb[v].wih[n(p)] + bih + bhh ----------
__global__ __launch_bounds__(256, 2) void gih_kernel(
    const f16* __restrict__ e0, const f16* __restrict__ e1, int E,
    const f16* __restrict__ w0, const f16* __restrict__ w1, int K,
    const float* __restrict__ bi, const float* __restrict__ bh,
    float* __restrict__ gih, int NP)
{
  MFMA_LDS_DECL
  MFMA_DECLS
  const int NT = E / 32;
#define STAGE_T(buf, t) MFMA_STAGE_TO(buf, e0, e1, E, (t) * 32, w0, w1, K, (t) * 32)
  PIPE(NT)
#undef STAGE_T
  const int q4 = (lane >> 4) * 4;
  const float s12 = 1.0f / 4096.0f;
  const int cn0 = bn + wn;
#pragma unroll
  for (int j = 0; j < 4; ++j) {
    const int col = cn0 + j * 16 + fr;
    const float bb = bi[col] + bh[col];
#pragma unroll
    for (int i = 0; i < 4; ++i)
#pragma unroll
      for (int r = 0; r < 4; ++r) {
        const int row = bm + wm + i * 16 + q4 + r;
        gih[(size_t)row * NP + col] = (acc0[i][j][r] + acc1[i][j][r] * s12) + bb;
      }
  }
}

// ---------------- gates GEMM + fused LSTM cell epilogue --------------------
// gates = h @ w_hh^T (K=H) + gih[tok[row]] (embedding term + both biases).
__global__ __launch_bounds__(256, 2) void gates_kernel(
    const f16* __restrict__ hin0, const f16* __restrict__ hin1, int H,
    const f16* __restrict__ w0, const f16* __restrict__ w1, int K, int E,
    const float* __restrict__ gih, int NP, const int* __restrict__ tok,
    float* __restrict__ cbuf,
    f16* __restrict__ hout0, f16* __restrict__ hout1)
{
  MFMA_LDS_DECL
  MFMA_DECLS
  const int NT = H / 32;
#define STAGE_T(buf, t) MFMA_STAGE_TO(buf, hin0, hin1, H, (t) * 32, w0, w1, K, E + (t) * 32)
  PIPE(NT)
#undef STAGE_T
  // epilogue: packed cols -> unit u = (cn0>>2)+fr, gate q = j.
  const int q4 = (lane >> 4) * 4;
  const float s12 = 1.0f / 4096.0f;
  const int cn0 = bn + wn;
  const int nunit = (cn0 >> 2) + fr;
#pragma unroll
  for (int i = 0; i < 4; ++i) {
#pragma unroll
    for (int r = 0; r < 4; ++r) {
      const int row = bm + wm + i * 16 + q4 + r;
      const float* gr = gih + (size_t)tok[row] * NP + cn0 + fr;
      float gv[4];
#pragma unroll
      for (int j = 0; j < 4; ++j)
        gv[j] = (acc0[i][j][r] + acc1[i][j][r] * s12) + gr[j * 16];
      const size_t off = (size_t)row * H + nunit;
      const float c = cbuf[off];
      const float cn = __fadd_rn(__fmul_rn(sigm(gv[1]), c),
                                 __fmul_rn(sigm(gv[0]), tanhf(gv[2])));
      const float hn = __fmul_rn(sigm(gv[3]), tanhf(cn));
      cbuf[off] = cn;
      f16 hh, hl; split_f16(hn, hh, hl);
      hout0[off] = hh; hout1[off] = hl;
    }
  }
}

// ------------- logits GEMM + fused argmax-partials epilogue ----------------
__global__ __launch_bounds__(256, 2) void logits_kernel(
    const f16* __restrict__ h0p, const f16* __restrict__ h1p, int H,
    const f16* __restrict__ w0, const f16* __restrict__ w1,
    const float* __restrict__ lpb,
    float* __restrict__ partM, int* __restrict__ partI,
    int step, int B, int V)
{
  MFMA_LDS_DECL
  MFMA_DECLS
  const int NT = H / 32;
#define STAGE_T(buf, t) MFMA_STAGE_TO(buf, h0p, h1p, H, (t) * 32, w0, w1, H, (t) * 32)
  PIPE(NT)
#undef STAGE_T
  const int q4 = (lane >> 4) * 4;
  const float s12 = 1.0f / 4096.0f;
  const int cn0 = bn + wn;
  float bv[4];
#pragma unroll
  for (int j = 0; j < 4; ++j) bv[j] = lpb[cn0 + j * 16 + fr];
  // w = logit + gumbel, overwrite acc0
#pragma unroll
  for (int i = 0; i < 4; ++i)
#pragma unroll
    for (int j = 0; j < 4; ++j) {
      const int col = cn0 + j * 16 + fr;
#pragma unroll
      for (int r = 0; r < 4; ++r) {
        const int row = bm + wm + i * 16 + q4 + r;
        const float logit = (acc0[i][j][r] + acc1[i][j][r] * s12) + bv[j];
        const unsigned gidx = ((unsigned)(step * B + row)) * (unsigned)V + (unsigned)col;
        acc0[i][j][r] = logit + gumbel_at(gidx);
      }
    }
  // per-row argmax over this wave's 64 cols (within each 16-lane group).
  // sc == 1.0 exactly, so no denominator partials needed.
  const int grp = cn0 >> 6;   // 64 col-groups of 64
#pragma unroll
  for (int i = 0; i < 4; ++i) {
#pragma unroll
    for (int r = 0; r < 4; ++r) {
      float mx = -INFINITY; int ix = 0;
#pragma unroll
      for (int j = 0; j < 4; ++j) {
        const float w = acc0[i][j][r];
        const int col = cn0 + j * 16 + fr;
        if (w > mx) { mx = w; ix = col; }
      }
#pragma unroll
      for (int m = 1; m < 16; m <<= 1) {
        const float om = __shfl_xor(mx, m, 64);
        const int oi = __shfl_xor(ix, m, 64);
        if (om > mx || (om == mx && oi < ix)) { mx = om; ix = oi; }
      }
      if (fr == 0) {
        const int row = bm + wm + i * 16 + q4 + r;
        partM[(size_t)row * 64 + grp] = mx;
        partI[(size_t)row * 64 + grp] = ix;
      }
    }
  }
}

// ----------- finalize: argmax reduce, write one-hot, publish tok -----------
__global__ __launch_bounds__(256) void finalize_kernel(
    const float* __restrict__ partM, const int* __restrict__ partI,
    float* __restrict__ out, int* __restrict__ tok,
    int step, int Tp1, int V)
{
  const int b = blockIdx.x;
  const int tid = threadIdx.x;
  __shared__ int s_tok;

  if (tid < 64) {
    float mx = partM[(size_t)b * 64 + tid];
    int ix = partI[(size_t)b * 64 + tid];
#pragma unroll
    for (int m = 1; m < 64; m <<= 1) {
      const float om = __shfl_xor(mx, m, 64);
      const int oi = __shfl_xor(ix, m, 64);
      if (om > mx || (om == mx && oi < ix)) { mx = om; ix = oi; }
    }
    if (tid == 0) { s_tok = ix; tok[b] = ix; }
  }
  __syncthreads();
  const int tk = s_tok;

  // one-hot write with exact 1.0 (sc == (1-y)+y == 1.0f identically)
  float* orow = out + ((size_t)b * Tp1 + step + 1) * V;
  const int tq = tk >> 2;
#pragma unroll
  for (int j = 0; j < 4; ++j) {
    const int idx = tid + 256 * j;
    float4 v = make_float4(0.f, 0.f, 0.f, 0.f);
    if (idx == tq) ((float*)&v)[tk & 3] = 1.0f;
    ((float4*)orow)[idx] = v;
  }
}

// ------------------------------- host side ---------------------------------

extern "C" void kernel_launch(void* const* d_in, const int* in_sizes, int n_in,
                              void* d_out, int out_size, void* d_ws, size_t ws_size,
                              hipStream_t stream) {
  const float* t     = (const float*)d_in[0];
  const float* emb   = (const float*)d_in[1];
  const float* affw  = (const float*)d_in[2];
  const float* affb  = (const float*)d_in[3];
  const float* wih   = (const float*)d_in[4];
  const float* whh   = (const float*)d_in[5];
  const float* bih   = (const float*)d_in[6];
  const float* bhh   = (const float*)d_in[7];
  const float* lpw   = (const float*)d_in[8];
  const float* lpb   = (const float*)d_in[9];
  const int*   start = (const int*)d_in[10];
  float* out = (float*)d_out;

  const int H = in_sizes[3];             // 1024
  const int V = in_sizes[9];             // 4096
  const int E = in_sizes[1] / V;         // 256
  const int F = in_sizes[2] / H;         // 2048
  const int B = in_sizes[0] / F;         // 1024
  const int Tp1 = out_size / (B * V);    // 33
  const int T = Tp1 - 1;                 // 32
  const int KG = E + H;                  // 1280
  const int NP = 4 * H;                  // 4096 packed gate cols

  // ---- workspace layout (~190 MB) ----
  char* p = (char*)d_ws;
  float* gihb  = (float*)p; p += (size_t)V * NP * 4;          // 64 MB gih table
  float* cbuf  = (float*)p; p += (size_t)B * H * 4;           // 4 MB
  f16* hA0[2]; f16* hA1[2];
  hA0[0] = (f16*)p; p += (size_t)B * H * 2;
  hA1[0] = (f16*)p; p += (size_t)B * H * 2;
  hA0[1] = (f16*)p; p += (size_t)B * H * 2;
  hA1[1] = (f16*)p; p += (size_t)B * H * 2;                   // 8 MB
  f16* wg0 = (f16*)p; p += (size_t)V * KG * 2;                // 21 MB packed gates
  f16* wg1 = (f16*)p; p += (size_t)V * KG * 2;
  f16* wl0 = (f16*)p; p += (size_t)V * H * 2;                 // 16 MB lp_w
  f16* wl1 = (f16*)p; p += (size_t)V * H * 2;
  f16* t0  = (f16*)p; p += (size_t)B * F * 2;                 // 8 MB t planes
  f16* t1  = (f16*)p; p += (size_t)B * F * 2;
  f16* aw0 = (f16*)p; p += (size_t)H * F * 2;                 // 8 MB aff_w planes
  f16* aw1 = (f16*)p; p += (size_t)H * F * 2;
  f16* em0 = (f16*)p; p += (size_t)V * E * 2;                 // 4 MB emb planes
  f16* em1 = (f16*)p; p += (size_t)V * E * 2;
  float* bgi = (float*)p; p += (size_t)NP * 4;
  float* bgh = (float*)p; p += (size_t)NP * 4;
  float* partM = (float*)p; p += (size_t)B * 64 * 4;
  int*   partI = (int*)p;   p += (size_t)B * 64 * 4;
  int*   tokb  = (int*)p;   p += (size_t)B * 4;
  (void)ws_size; (void)n_in;

  // ---- setup ----
  init_kernel<<<B, 256, 0, stream>>>(out, start, tokb, Tp1, V);
  pack_gates_kernel<<<dim3((KG + 255) / 256, NP), 256, 0, stream>>>(
      wih, whh, wg0, wg1, E, H, KG);
  pack_bias_kernel<<<NP / 256, 256, 0, stream>>>(bih, bhh, bgi, bgh, H);
  split_kernel<<<(V * H + 255) / 256, 256, 0, stream>>>(lpw, wl0, wl1, V * H);
  split_kernel<<<(B * F + 255) / 256, 256, 0, stream>>>(t, t0, t1, B * F);
  split_kernel<<<(H * F + 255) / 256, 256, 0, stream>>>(affw, aw0, aw1, H * F);
  split_kernel<<<(V * E + 255) / 256, 256, 0, stream>>>(emb, em0, em1, V * E);
  // h0 = t @ aff_w^T + aff_b -> split into hA[0]; zero cbuf
  h0_kernel<<<dim3(H / 128, B / 128), 256, 0, stream>>>(
      t0, t1, F, aw0, aw1, affb, hA0[0], hA1[0], H, cbuf);
  // gih = emb @ w_ih^T + b_ih + b_hh (packed cols), f32
  gih_kernel<<<dim3(NP / 128, V / 128), 256, 0, stream>>>(
      em0, em1, E, wg0, wg1, KG, bgi, bgh, gihb, NP);

  for (int s = 0; s < T; ++s) {
    const int cur = s & 1, nxt = (s + 1) & 1;
    gates_kernel<<<dim3(NP / 128, B / 128), 256, 0, stream>>>(
        hA0[cur], hA1[cur], H, wg0, wg1, KG, E, gihb, NP, tokb,
        cbuf, hA0[nxt], hA1[nxt]);
    logits_kernel<<<dim3(V / 128, B / 128), 256, 0, stream>>>(
        hA0[nxt], hA1[nxt], H, wl0, wl1, lpb,
        partM, partI, s, B, V);
    finalize_kernel<<<B, 256, 0, stream>>>(
        partM, partI, out, tokb, s, Tp1, V);
  }
}

// Round 7
// 3903.568 us; speedup vs baseline: 1.7542x; 1.0568x over previous
//
#include <hip/hip_runtime.h>
#include <math.h>

// ---------------------------------------------------------------------------
// Sender: LSTM + Gumbel straight-through decode, 32 steps.
// Round 15 (r14 regressed 4125 -> base is r12, 3779 us).
// Ledger: traffic cuts (r11,r13,r14) neutral/negative; barrier-count cut
// (r12) positive; r12's vmcnt(12) waits were no-ops (in-flight == 12), so
// its K-step = barrier -> stage -> compute. Theory: per-barrier convoy
// (~2000 cyc) dominates the 4100 cyc/K-step vs ~1700 resource floor.
// Changes vs r12 (geometry/swizzle/epilogues byte-identical):
//  (1) WINDOW pipeline: one barrier per TWO K-tiles. 4 LDS bufs; window =
//      { vmcnt(0) [honest: only the pair staged last window in flight,
//        covered by ~2500 cyc of MFMA] -> barrier -> stage pair {t+2,t+3}
//        -> compute buf t, buf t+1 }. Barriers/GEMM 32 -> 16.
//  (2) finalize folded into gates prologue (NP==V==4096 makes the out
//      col-slice line up): gates(s>=1) reduces partials(s-1) per-quad,
//      fills s_tok2[128] (LDS), writes its 128x128 out-slice. 31 fewer
//      dispatches; one finalize after the loop emits the last token.
// f16 2-way split (3 MFMA/product), same products & accumulation order as
// r12 (absmax 0.0 there).
// ---------------------------------------------------------------------------

typedef _Float16 f16;
typedef f16 f16x8 __attribute__((ext_vector_type(8)));
typedef float f32x4 __attribute__((ext_vector_type(4)));

#define F16_MIN_NORM 6.104e-5f

__device__ __forceinline__ void split_f16(float v, f16& h, f16& l) {
  f16 h0 = (fabsf(v) < F16_MIN_NORM) ? (f16)0.0f : (f16)v;
  float r = (v - (float)h0) * 4096.0f;
  h = h0; l = (f16)r;
}

__device__ __forceinline__ float sigm(float x) { return 1.0f / (1.0f + expf(-x)); }

#define GLOAD_LDS16(gsrc, ldst)                                               \
  __builtin_amdgcn_global_load_lds(                                           \
      (const __attribute__((address_space(1))) unsigned int*)(const void*)(gsrc), \
      (__attribute__((address_space(3))) unsigned int*)(void*)(ldst), 16, 0, 0)

// --------------------------- threefry / gumbel -----------------------------

__device__ __forceinline__ unsigned tf_rotl(unsigned x, int r) {
  return (x << r) | (x >> (32 - r));
}

// JAX threefry2x32-20, key (0,42), partitionable: draw = x0_out ^ x1_out.
__device__ inline float gumbel_at(unsigned idx) {
  const unsigned ks0 = 0u;
  const unsigned ks1 = 42u;
  const unsigned ks2 = 0x1BD11BDAu ^ ks0 ^ ks1;
  unsigned x0 = 0u + ks0;
  unsigned x1 = idx + ks1;
#define TFR(rot) { x0 += x1; x1 = tf_rotl(x1, rot); x1 ^= x0; }
  TFR(13) TFR(15) TFR(26) TFR(6)
  x0 += ks1; x1 += ks2 + 1u;
  TFR(17) TFR(29) TFR(16) TFR(24)
  x0 += ks2; x1 += ks0 + 2u;
  TFR(13) TFR(15) TFR(26) TFR(6)
  x0 += ks0; x1 += ks1 + 3u;
  TFR(17) TFR(29) TFR(16) TFR(24)
  x0 += ks1; x1 += ks2 + 4u;
  TFR(13) TFR(15) TFR(26) TFR(6)
  x0 += ks2; x1 += ks0 + 5u;
#undef TFR
  const unsigned bits = x0 ^ x1;
  const float f = __uint_as_float((bits >> 9) | 0x3F800000u) - 1.0f;
  const float tiny = 1.17549435082228751e-38f;
  const float u = fmaxf(tiny, f * (1.0f - tiny) + tiny);
  return -logf(-logf(u));
}

// ------------------------- setup / pack kernels ----------------------------

__global__ void init_kernel(float* __restrict__ out, const int* __restrict__ startp,
                            int* __restrict__ tok, int Tp1, int V) {
  const int b = blockIdx.x;
  const int start = *startp;
  if (threadIdx.x == 0) tok[b] = start;
  float* orow = out + (size_t)b * Tp1 * V;
  const int tq = start >> 2;
  for (int v4 = threadIdx.x; v4 < V / 4; v4 += blockDim.x) {
    float4 v = make_float4(0.f, 0.f, 0.f, 0.f);
    if (v4 == tq) ((float*)&v)[start & 3] = 1.0f;
    ((float4*)orow)[v4] = v;
  }
}

// packed gate col p: gate q=(p>>4)&3, unit u=((p>>6)<<4)+(p&15); orig row
// n' = q*H + u. wpk[p][k] = k<E ? wih[n'][k] : whh[n'][k-E], split.
__global__ void pack_gates_kernel(const float* __restrict__ wih,
                                  const float* __restrict__ whh,
                                  f16* __restrict__ w0, f16* __restrict__ w1,
                                  int E, int H, int K) {
  const int k = blockIdx.x * blockDim.x + threadIdx.x;
  const int p = blockIdx.y;
  if (k >= K) return;
  const int n = ((p >> 4) & 3) * H + ((p >> 6) << 4) + (p & 15);
  const float v = (k < E) ? wih[(size_t)n * E + k] : whh[(size_t)n * H + (k - E)];
  f16 h, l; split_f16(v, h, l);
  w0[(size_t)p * K + k] = h;
  w1[(size_t)p * K + k] = l;
}

__global__ void pack_bias_kernel(const float* __restrict__ bih,
                                 const float* __restrict__ bhh,
                                 float* __restrict__ bi, float* __restrict__ bh, int H) {
  const int p = blockIdx.x * blockDim.x + threadIdx.x;
  const int n = ((p >> 4) & 3) * H + ((p >> 6) << 4) + (p & 15);
  bi[p] = bih[n];
  bh[p] = bhh[n];
}

__global__ void split_kernel(const float* __restrict__ in,
                             f16* __restrict__ o0, f16* __restrict__ o1, int n) {
  const int i = blockIdx.x * blockDim.x + threadIdx.x;
  if (i < n) { f16 h, l; split_f16(in[i], h, l); o0[i] = h; o1[i] = l; }
}

// ----------------------- shared K-loop building block ----------------------
// block 512 thr / 8 waves, tile 128x128, BK=32, 4-buf LDS (128 KB), windowed.
// Staging: 32 1KB chunks (A-hi 8, A-lo 8, B-hi 8, B-lo 8), 4 per wave.
// Wave (wr=wid&3, wc=wid>>2) computes rows [wr*32,+32) x cols [wc*64,+64).
// Swizzle: LDS[row][slot] holds global 16B-slot (slot ^ ((row>>1)&3)).
//   stage source slot = (lane&3) ^ ((lane>>3)&3)   (srow = lane>>2)
//   read slot         = (lane>>4) ^ ((lane>>1)&3)  (row & 15 == lane & 15)

__device__ __forceinline__ void stage_chunk(
    int chunk, int srow, int scol,
    const f16* __restrict__ a0s, const f16* __restrict__ a1s, int lda, int ka, int bm,
    const f16* __restrict__ b0s, const f16* __restrict__ b1s, int ldb, int kb, int bn,
    f16 (*ldsA0)[32], f16 (*ldsA1)[32], f16 (*ldsB0)[32], f16 (*ldsB1)[32])
{
  if (chunk < 8) {
    GLOAD_LDS16(a0s + (size_t)(bm + chunk * 16 + srow) * lda + ka + scol,
                &ldsA0[chunk * 16][0]);
  } else if (chunk < 16) {
    const int s = chunk - 8;
    GLOAD_LDS16(a1s + (size_t)(bm + s * 16 + srow) * lda + ka + scol,
                &ldsA1[s * 16][0]);
  } else if (chunk < 24) {
    const int s = chunk - 16;
    GLOAD_LDS16(b0s + (size_t)(bn + s * 16 + srow) * ldb + kb + scol,
                &ldsB0[s * 16][0]);
  } else {
    const int s = chunk - 24;
    GLOAD_LDS16(b1s + (size_t)(bn + s * 16 + srow) * ldb + kb + scol,
                &ldsB1[s * 16][0]);
  }
}

#define MFMA_DECLS                                                            \
  const int tid  = threadIdx.x;                                               \
  const int lane = tid & 63;                                                  \
  const int wid  = tid >> 6;                                                  \
  const int bm   = blockIdx.y * 128;                                          \
  const int bn   = blockIdx.x * 128;                                          \
  const int wm   = (wid & 3) * 32;                                            \
  const int wn   = (wid >> 2) * 64;                                           \
  const int fr   = lane & 15;                                                 \
  const int fk   = (((lane >> 4) ^ ((lane >> 1) & 3)) * 8);                   \
  const int srow = lane >> 2;                                                 \
  const int scol = (((lane & 3) ^ ((lane >> 3) & 3)) * 8);                    \
  f32x4 acc0[2][4], acc1[2][4];                                               \
  _Pragma("unroll") for (int i = 0; i < 2; ++i)                               \
  _Pragma("unroll") for (int j = 0; j < 4; ++j) {                             \
    acc0[i][j] = (f32x4)0.0f; acc1[i][j] = (f32x4)0.0f; }

#define MFMA_LDS_DECL                                                         \
  __shared__ f16 ldsA0[4][128][32], ldsA1[4][128][32],                        \
                 ldsB0[4][128][32], ldsB1[4][128][32];

// Issue-only staging into buffer `buf` (no barriers here).
#define MFMA_STAGE_TO(buf, a0s, a1s, lda, ka, b0s, b1s, ldb, kb)              \
  { _Pragma("unroll") for (int c = 0; c < 4; ++c)                             \
      stage_chunk(wid * 4 + c, srow, scol, (a0s), (a1s), (lda), (ka), bm,     \
                  (b0s), (b1s), (ldb), (kb), bn,                              \
                  ldsA0[(buf)], ldsA1[(buf)], ldsB0[(buf)], ldsB1[(buf)]); }

#define MFMA_COMPUTE_FROM(buf)                                                \
  {                                                                           \
    f16x8 a0[2], a1[2], b0[4], b1[4];                                         \
    _Pragma("unroll") for (int i = 0; i < 2; ++i) {                           \
      a0[i] = *(const f16x8*)&ldsA0[(buf)][wm + i * 16 + fr][fk];             \
      a1[i] = *(const f16x8*)&ldsA1[(buf)][wm + i * 16 + fr][fk];             \
    }                                                                         \
    _Pragma("unroll") for (int j = 0; j < 4; ++j) {                           \
      b0[j] = *(const f16x8*)&ldsB0[(buf)][wn + j * 16 + fr][fk];             \
      b1[j] = *(const f16x8*)&ldsB1[(buf)][wn + j * 16 + fr][fk];             \
    }                                                                         \
    _Pragma("unroll") for (int i = 0; i < 2; ++i)                             \
    _Pragma("unroll") for (int j = 0; j < 4; ++j) {                           \
      acc0[i][j] = __builtin_amdgcn_mfma_f32_16x16x32_f16(a0[i], b0[j], acc0[i][j], 0, 0, 0); \
      acc1[i][j] = __builtin_amdgcn_mfma_f32_16x16x32_f16(a0[i], b1[j], acc1[i][j], 0, 0, 0); \
      acc1[i][j] = __builtin_amdgcn_mfma_f32_16x16x32_f16(a1[i], b0[j], acc1[i][j], 0, 0, 0); \
    }                                                                         \
  }

// One window: drain the pair staged last window (honest vmcnt(0), covered
// by the previous window's ~2 MFMA clusters) -> ONE barrier (cross-wave
// visibility of the pair we compute AND confirms everyone finished the
// pair we stage into) -> stage next pair (flies under compute) -> compute
// two K-tiles.
#define PIPE_WINDOW(bufA, bufB, DO_STAGE_PAIR)                                \
  asm volatile("s_waitcnt vmcnt(0)" ::: "memory");                            \
  __builtin_amdgcn_s_barrier();                                               \
  asm volatile("" ::: "memory");                                              \
  DO_STAGE_PAIR                                                               \
  asm volatile("" ::: "memory");                                              \
  __builtin_amdgcn_s_setprio(1);                                              \
  MFMA_COMPUTE_FROM(bufA)                                                     \
  MFMA_COMPUTE_FROM(bufB)                                                     \
  __builtin_amdgcn_s_setprio(0);                                              \
  asm volatile("" ::: "memory");

#define PIPE_PROLOGUE  STAGE_T(0, 0) STAGE_T(1, 1)

// NT must be a multiple of 4, NT >= 8. STAGE_T(buf, t) #defined per kernel.
#define PIPE_BODY(NT)                                                         \
  for (int tt = 0; tt < (NT); tt += 4) {                                      \
    PIPE_WINDOW(0, 1,                                                         \
      if (tt + 2 < (NT)) { STAGE_T(2, tt + 2) STAGE_T(3, tt + 3) })           \
    PIPE_WINDOW(2, 3,                                                         \
      if (tt + 4 < (NT)) { STAGE_T(0, tt + 4) STAGE_T(1, tt + 5) })           \
  }

#define PIPE(NT) PIPE_PROLOGUE PIPE_BODY(NT)

// ------------------- h0 GEMM: h0 = t @ aff_w^T + aff_b ---------------------
__global__ __launch_bounds__(512, 2) void h0_kernel(
    const f16* __restrict__ t0, const f16* __restrict__ t1, int F,
    const f16* __restrict__ aw0, const f16* __restrict__ aw1,
    const float* __restrict__ affb,
    f16* __restrict__ h0p, f16* __restrict__ h1p, int H,
    float* __restrict__ czero)
{
  MFMA_LDS_DECL
  MFMA_DECLS
  const int NT = F / 32;
#define STAGE_T(buf, t) MFMA_STAGE_TO(buf, t0, t1, F, (t) * 32, aw0, aw1, F, (t) * 32)
  PIPE(NT)
#undef STAGE_T
  const int q4 = (lane >> 4) * 4;
  const float s12 = 1.0f / 4096.0f;
  const int cn0 = bn + wn;
#pragma unroll
  for (int j = 0; j < 4; ++j) {
    const int col = cn0 + j * 16 + fr;
    const float bb = affb[col];
#pragma unroll
    for (int i = 0; i < 2; ++i) {
#pragma unroll
      for (int r = 0; r < 4; ++r) {
        const int row = bm + wm + i * 16 + q4 + r;
        const float v = (acc0[i][j][r] + acc1[i][j][r] * s12) + bb;
        f16 hh, hl; split_f16(v, hh, hl);
        const size_t off = (size_t)row * H + col;
        h0p[off] = hh; h1p[off] = hl;
        czero[off] = 0.0f;
      }
    }
  }
}

// ------- gih table GEMM: gih[v][p] = emb[v].wih[n(p)] + bih + bhh ----------
__global__ __launch_bounds__(512, 2) void gih_kernel(
    const f16* __restrict__ e0, const f16* __restrict__ e1, int E,
    const f16* __restrict__ w0, const f16* __restrict__ w1, int K,
    const float* __restrict__ bi, const float* __restrict__ bh,
    float* __restrict__ gih, int NP)
{
  MFMA_LDS_DECL
  MFMA_DECLS
  const int NT = E / 32;
#define STAGE_T(buf, t) MFMA_STAGE_TO(buf, e0, e1, E, (t) * 32, w0, w1, K, (t) * 32)
  PIPE(NT)
#undef STAGE_T
  const int q4 = (lane >> 4) * 4;
  const float s12 = 1.0f / 4096.0f;
  const int cn0 = bn + wn;
#pragma unroll
  for (int j = 0; j < 4; ++j) {
    const int col = cn0 + j * 16 + fr;
    const float bb = bi[col] + bh[col];
#pragma unroll
    for (int i = 0; i < 2; ++i)
#pragma unroll
      for (int r = 0; r < 4; ++r) {
        const int row = bm + wm + i * 16 + q4 + r;
        gih[(size_t)row * NP + col] = (acc0[i][j][r] + acc1[i][j][r] * s12) + bb;
      }
  }
}

// ---------------- gates GEMM + folded finalize + LSTM epilogue -------------
// Prologue (step>0): reduce partials(step-1) -> tok per row (s_tok2, LDS),
// write this block's 128x128 one-hot out-slice for position `step`.
// (Valid because NP == V == 4096: bn spans both.) step==0: tok from tokb.
// GEMM: gates = h @ w_hh^T (K=H) + gih[tok[row]] (emb term + both biases).
__global__ __launch_bounds__(512, 2) void gates_kernel(
    const f16* __restrict__ hin0, const f16* __restrict__ hin1, int H,
    const f16* __restrict__ w0, const f16* __restrict__ w1, int K, int E,
    const float* __restrict__ gih, int NP, const int* __restrict__ tokb,
    const float* __restrict__ partM, const int* __restrict__ partI,
    float* __restrict__ out, int step, int Tp1, int V,
    float* __restrict__ cbuf,
    f16* __restrict__ hout0, f16* __restrict__ hout1)
{
  MFMA_LDS_DECL
  __shared__ int s_tok2[128];
  MFMA_DECLS
  const int NT = H / 32;
#define STAGE_T(buf, t) MFMA_STAGE_TO(buf, hin0, hin1, H, (t) * 32, w0, w1, K, E + (t) * 32)
  PIPE_PROLOGUE
  // ---- folded finalize(step-1), runs under the prologue stage loads ----
  if (step == 0) {
    for (int r = tid; r < 128; r += 512) s_tok2[r] = tokb[bm + r];
  } else {
    const int rloc = wid * 16 + (lane >> 2);        // 8 waves x 16 rows
    const int row = bm + rloc;
    const int g0 = (lane & 3) * 16;                  // 4 lanes x 16 groups
    float mx = -INFINITY; int ix = 0;
#pragma unroll
    for (int g = 0; g < 16; ++g) {
      const float om = partM[(size_t)row * 64 + g0 + g];
      const int oi = partI[(size_t)row * 64 + g0 + g];
      if (om > mx || (om == mx && oi < ix)) { mx = om; ix = oi; }
    }
#pragma unroll
    for (int m = 1; m < 4; m <<= 1) {                // quad butterfly
      const float om = __shfl_xor(mx, m, 64);
      const int oi = __shfl_xor(ix, m, 64);
      if (om > mx || (om == mx && oi < ix)) { mx = om; ix = oi; }
    }
    if ((lane & 3) == 0) s_tok2[rloc] = ix;
    // one-hot out slice: row `row`, cols [bn, bn+128), exact 1.0
    float* orow = out + ((size_t)row * Tp1 + step) * V + bn;
    const int tl = ix - bn;                          // tok local col (may be OOR)
    const int tq = tl >> 2;
#pragma unroll
    for (int k = 0; k < 8; ++k) {
      const int c4 = (lane & 3) * 8 + k;
      float4 v = make_float4(0.f, 0.f, 0.f, 0.f);
      if ((unsigned)tl < 128u && c4 == tq) ((float*)&v)[tl & 3] = 1.0f;
      ((float4*)orow)[c4] = v;
    }
  }
  // s_tok2 visibility: window 0's barrier precedes all epilogue reads.
  PIPE_BODY(NT)
#undef STAGE_T
  // epilogue: packed cols -> unit u = (cn0>>2)+fr, gate q = j.
  const int q4 = (lane >> 4) * 4;
  const float s12 = 1.0f / 4096.0f;
  const int cn0 = bn + wn;
  const int nunit = (cn0 >> 2) + fr;
#pragma unroll
  for (int i = 0; i < 2; ++i) {
#pragma unroll
    for (int r = 0; r < 4; ++r) {
      const int rl = wm + i * 16 + q4 + r;
      const int row = bm + rl;
      const float* gr = gih + (size_t)s_tok2[rl] * NP + cn0 + fr;
      float gv[4];
#pragma unroll
      for (int j = 0; j < 4; ++j)
        gv[j] = (acc0[i][j][r] + acc1[i][j][r] * s12) + gr[j * 16];
      const size_t off = (size_t)row * H + nunit;
      const float c = cbuf[off];
      const float cn = __fadd_rn(__fmul_rn(sigm(gv[1]), c),
                                 __fmul_rn(sigm(gv[0]), tanhf(gv[2])));
      const float hn = __fmul_rn(sigm(gv[3]), tanhf(cn));
      cbuf[off] = cn;
      f16 hh, hl; split_f16(hn, hh, hl);
      hout0[off] = hh; hout1[off] = hl;
    }
  }
}

// ------------- logits GEMM + fused argmax-partials epilogue ----------------
__global__ __launch_bounds__(512, 2) void logits_kernel(
    const f16* __restrict__ h0p, const f16* __restrict__ h1p, int H,
    const f16* __restrict__ w0, const f16* __restrict__ w1,
    const float* __restrict__ lpb,
    float* __restrict__ partM, int* __restrict__ partI,
    int step, int B, int V)
{
  MFMA_LDS_DECL
  MFMA_DECLS
  const int NT = H / 32;
#define STAGE_T(buf, t) MFMA_STAGE_TO(buf, h0p, h1p, H, (t) * 32, w0, w1, H, (t) * 32)
  PIPE(NT)
#undef STAGE_T
  const int q4 = (lane >> 4) * 4;
  const float s12 = 1.0f / 4096.0f;
  const int cn0 = bn + wn;
  float bv[4];
#pragma unroll
  for (int j = 0; j < 4; ++j) bv[j] = lpb[cn0 + j * 16 + fr];
  // w = logit + gumbel, overwrite acc0
#pragma unroll
  for (int i = 0; i < 2; ++i)
#pragma unroll
    for (int j = 0; j < 4; ++j) {
      const int col = cn0 + j * 16 + fr;
#pragma unroll
      for (int r = 0; r < 4; ++r) {
        const int row = bm + wm + i * 16 + q4 + r;
        const float logit = (acc0[i][j][r] + acc1[i][j][r] * s12) + bv[j];
        const unsigned gidx = ((unsigned)(step * B + row)) * (unsigned)V + (unsigned)col;
        acc0[i][j][r] = logit + gumbel_at(gidx);
      }
    }
  // per-row argmax over this wave's 64 cols (within each 16-lane group).
  // sc == 1.0 exactly, so no denominator partials needed.
  const int grp = cn0 >> 6;   // 64 col-groups of 64
#pragma unroll
  for (int i = 0; i < 2; ++i) {
#pragma unroll
    for (int r = 0; r < 4; ++r) {
      float mx = -INFINITY; int ix = 0;
#pragma unroll
      for (int j = 0; j < 4; ++j) {
        const float w = acc0[i][j][r];
        const int col = cn0 + j * 16 + fr;
        if (w > mx) { mx = w; ix = col; }
      }
#pragma unroll
      for (int m = 1; m < 16; m <<= 1) {
        const float om = __shfl_xor(mx, m, 64);
        const int oi = __shfl_xor(ix, m, 64);
        if (om > mx || (om == mx && oi < ix)) { mx = om; ix = oi; }
      }
      if (fr == 0) {
        const int row = bm + wm + i * 16 + q4 + r;
        partM[(size_t)row * 64 + grp] = mx;
        partI[(size_t)row * 64 + grp] = ix;
      }
    }
  }
}

// ----------- finalize: argmax reduce, write one-hot, publish tok -----------
// (used once, after the loop, for the last emitted token)
__global__ __launch_bounds__(256) void finalize_kernel(
    const float* __restrict__ partM, const int* __restrict__ partI,
    float* __restrict__ out, int* __restrict__ tok,
    int step, int Tp1, int V)
{
  const int b = blockIdx.x;
  const int tid = threadIdx.x;
  __shared__ int s_tok;

  if (tid < 64) {
    float mx = partM[(size_t)b * 64 + tid];
    int ix = partI[(size_t)b * 64 + tid];
#pragma unroll
    for (int m = 1; m < 64; m <<= 1) {
      const float om = __shfl_xor(mx, m, 64);
      const int oi = __shfl_xor(ix, m, 64);
      if (om > mx || (om == mx && oi < ix)) { mx = om; ix = oi; }
    }
    if (tid == 0) { s_tok = ix; tok[b] = ix; }
  }
  __syncthreads();
  const int tk = s_tok;

  // one-hot write with exact 1.0 (sc == (1-y)+y == 1.0f identically)
  float* orow = out + ((size_t)b * Tp1 + step + 1) * V;
  const int tq = tk >> 2;
#pragma unroll
  for (int j = 0; j < 4; ++j) {
    const int idx = tid + 256 * j;
    float4 v = make_float4(0.f, 0.f, 0.f, 0.f);
    if (idx == tq) ((float*)&v)[tk & 3] = 1.0f;
    ((float4*)orow)[idx] = v;
  }
}

// ------------------------------- host side ---------------------------------

extern "C" void kernel_launch(void* const* d_in, const int* in_sizes, int n_in,
                              void* d_out, int out_size, void* d_ws, size_t ws_size,
                              hipStream_t stream) {
  const float* t     = (const float*)d_in[0];
  const float* emb   = (const float*)d_in[1];
  const float* affw  = (const float*)d_in[2];
  const float* affb  = (const float*)d_in[3];
  const float* wih   = (const float*)d_in[4];
  const float* whh   = (const float*)d_in[5];
  const float* bih   = (const float*)d_in[6];
  const float* bhh   = (const float*)d_in[7];
  const float* lpw   = (const float*)d_in[8];
  const float* lpb   = (const float*)d_in[9];
  const int*   start = (const int*)d_in[10];
  float* out = (float*)d_out;

  const int H = in_sizes[3];             // 1024
  const int V = in_sizes[9];             // 4096
  const int E = in_sizes[1] / V;         // 256
  const int F = in_sizes[2] / H;         // 2048
  const int B = in_sizes[0] / F;         // 1024
  const int Tp1 = out_size / (B * V);    // 33
  const int T = Tp1 - 1;                 // 32
  const int KG = E + H;                  // 1280
  const int NP = 4 * H;                  // 4096 packed gate cols (== V)

  // ---- workspace layout (~190 MB) ----
  char* p = (char*)d_ws;
  float* gihb  = (float*)p; p += (size_t)V * NP * 4;          // 64 MB gih table
  float* cbuf  = (float*)p; p += (size_t)B * H * 4;           // 4 MB
  f16* hA0[2]; f16* hA1[2];
  hA0[0] = (f16*)p; p += (size_t)B * H * 2;
  hA1[0] = (f16*)p; p += (size_t)B * H * 2;
  hA0[1] = (f16*)p; p += (size_t)B * H * 2;
  hA1[1] = (f16*)p; p += (size_t)B * H * 2;                   // 8 MB
  f16* wg0 = (f16*)p; p += (size_t)V * KG * 2;                // 21 MB packed gates
  f16* wg1 = (f16*)p; p += (size_t)V * KG * 2;
  f16* wl0 = (f16*)p; p += (size_t)V * H * 2;                 // 16 MB lp_w
  f16* wl1 = (f16*)p; p += (size_t)V * H * 2;
  f16* t0  = (f16*)p; p += (size_t)B * F * 2;                 // 8 MB t planes
  f16* t1  = (f16*)p; p += (size_t)B * F * 2;
  f16* aw0 = (f16*)p; p += (size_t)H * F * 2;                 // 8 MB aff_w planes
  f16* aw1 = (f16*)p; p += (size_t)H * F * 2;
  f16* em0 = (f16*)p; p += (size_t)V * E * 2;                 // 4 MB emb planes
  f16* em1 = (f16*)p; p += (size_t)V * E * 2;
  float* bgi = (float*)p; p += (size_t)NP * 4;
  float* bgh = (float*)p; p += (size_t)NP * 4;
  float* partM = (float*)p; p += (size_t)B * 64 * 4;
  int*   partI = (int*)p;   p += (size_t)B * 64 * 4;
  int*   tokb  = (int*)p;   p += (size_t)B * 4;
  (void)ws_size; (void)n_in;

  // ---- setup ----
  init_kernel<<<B, 256, 0, stream>>>(out, start, tokb, Tp1, V);
  pack_gates_kernel<<<dim3((KG + 255) / 256, NP), 256, 0, stream>>>(
      wih, whh, wg0, wg1, E, H, KG);
  pack_bias_kernel<<<NP / 256, 256, 0, stream>>>(bih, bhh, bgi, bgh, H);
  split_kernel<<<(V * H + 255) / 256, 256, 0, stream>>>(lpw, wl0, wl1, V * H);
  split_kernel<<<(B * F + 255) / 256, 256, 0, stream>>>(t, t0, t1, B * F);
  split_kernel<<<(H * F + 255) / 256, 256, 0, stream>>>(affw, aw0, aw1, H * F);
  split_kernel<<<(V * E + 255) / 256, 256, 0, stream>>>(emb, em0, em1, V * E);
  // h0 = t @ aff_w^T + aff_b -> split into hA[0]; zero cbuf
  h0_kernel<<<dim3(H / 128, B / 128), 512, 0, stream>>>(
      t0, t1, F, aw0, aw1, affb, hA0[0], hA1[0], H, cbuf);
  // gih = emb @ w_ih^T + b_ih + b_hh (packed cols), f32
  gih_kernel<<<dim3(NP / 128, V / 128), 512, 0, stream>>>(
      em0, em1, E, wg0, wg1, KG, bgi, bgh, gihb, NP);

  for (int s = 0; s < T; ++s) {
    const int cur = s & 1, nxt = (s + 1) & 1;
    gates_kernel<<<dim3(NP / 128, B / 128), 512, 0, stream>>>(
        hA0[cur], hA1[cur], H, wg0, wg1, KG, E, gihb, NP, tokb,
        partM, partI, out, s, Tp1, V,
        cbuf, hA0[nxt], hA1[nxt]);
    logits_kernel<<<dim3(V / 128, B / 128), 512, 0, stream>>>(
        hA0[nxt], hA1[nxt], H, wl0, wl1, lpb,
        partM, partI, s, B, V);
  }
  finalize_kernel<<<B, 256, 0, stream>>>(
      partM, partI, out, tokb, T - 1, Tp1, V);
}